// Round 4
// baseline (32.424 us; speedup 1.0000x reference)
//
#include <hip/hip_runtime.h>

#define BATCH 4096
#define INS   256
#define OUTS  256
#define NODES 128
#define NT    64      // output-column tile per workgroup
#define MCH   16      // sample rows per chunk (one 16-row MFMA tile)
#define MSPLIT 2      // m-split blocks per (expert, column-quarter)
#define MAXC  512     // per-expert list capacity in workspace (16 sigma margin)

typedef short short8 __attribute__((ext_vector_type(8)));
typedef float f32x4  __attribute__((ext_vector_type(4)));

__device__ __forceinline__ unsigned short f2bf(float f) {
    unsigned int u = __builtin_bit_cast(unsigned int, f);
    u += 0x7fffu + ((u >> 16) & 1u);   // round-to-nearest-even
    return (unsigned short)(u >> 16);
}

__device__ __forceinline__ short8 pack8(float4 a, float4 b) {
    short8 r;
    r[0] = (short)f2bf(a.x); r[1] = (short)f2bf(a.y);
    r[2] = (short)f2bf(a.z); r[3] = (short)f2bf(a.w);
    r[4] = (short)f2bf(b.x); r[5] = (short)f2bf(b.y);
    r[6] = (short)f2bf(b.z); r[7] = (short)f2bf(b.w);
    return r;
}

// ---- pre-kernel: bucket samples by expert into workspace ----
// gcnt[e] (int) at ws+0, glist[e][MAXC] (u16) at ws+512.
// Order within a list is non-deterministic but ALL consumers read the same
// list, so position-based m-splitting is consistent (no round-2 race).
__global__ __launch_bounds__(256) void moe_scan(
    const int* __restrict__ nid, int* __restrict__ gcnt,
    unsigned short* __restrict__ glist)
{
    int s = blockIdx.x * 256 + threadIdx.x;
    int e = nid[BATCH + s];
    int p = atomicAdd(&gcnt[e], 1);
    if (p < MAXC) glist[e * MAXC + p] = (unsigned short)s;
}

// ---- main kernel: no scan, no LDS, no barriers ----
__global__ __launch_bounds__(256, 4) void moe_fwd(
    const float* __restrict__ x, const float* __restrict__ W1,
    const float* __restrict__ b1, float* __restrict__ out,
    const int* __restrict__ gcnt, const unsigned short* __restrict__ glist)
{
    const int t   = threadIdx.x;
    const int bid = blockIdx.x;
    // XCD-chunked swizzle: all 8 blocks (4 col-quarters x 2 m-halves) of an
    // expert land on one XCD for L2 reuse of W, x, and the list.
    const int sub = bid >> 3;              // 0..127 within XCD
    const int e   = (bid & 7) * 16 + (sub >> 3);
    const int c0  = ((sub >> 1) & 3) * NT;
    const int mh  = sub & 1;               // m-half by list position (safe now)

    const int w  = t >> 6;     // wave 0..3 -> 16-col block
    const int l  = t & 63;
    const int g  = l >> 4;     // k-group
    const int ln = l & 15;
    const int cc = c0 + w * 16 + ln;

    // deepest dependency chain first: cnt -> list -> x
    const int cnt  = gcnt[e];
    const int half = (cnt + 1) >> 1;
    const int lo   = mh * half;
    const int hi   = (cnt < lo + half) ? cnt : lo + half;

    // W loads: each lane loads exactly its own B-fragment elements.
    const float* __restrict__ wp = W1 + (size_t)e * (INS * OUTS) + cc;
    short8 wf[8];
    #pragma unroll
    for (int ks = 0; ks < 8; ++ks) {
        short8 v;
        #pragma unroll
        for (int j = 0; j < 8; ++j)
            v[j] = (short)f2bf(wp[(size_t)(ks * 32 + g * 8 + j) * OUTS]);
        wf[ks] = v;
    }
    const float bval = b1[e * OUTS + cc];

    if (lo >= hi) return;              // uniform across WG

    const unsigned short* __restrict__ lst = glist + e * MAXC;

    for (int m0 = lo; m0 < hi; m0 += MCH) {
        int r0 = m0 + ln;
        // clamp tail rows: garbage rows only feed discarded D rows
        int s0 = lst[r0 < hi ? r0 : hi - 1];
        const float* __restrict__ xp0 = x + (size_t)s0 * INS + g * 8;

        f32x4 acc0 = {0.f, 0.f, 0.f, 0.f};
        #pragma unroll
        for (int ks = 0; ks < 8; ++ks) {
            float4 u0 = *reinterpret_cast<const float4*>(xp0 + ks * 32);
            float4 u1 = *reinterpret_cast<const float4*>(xp0 + ks * 32 + 4);
            short8 a0 = pack8(u0, u1);
            acc0 = __builtin_amdgcn_mfma_f32_16x16x32_bf16(a0, wf[ks], acc0, 0, 0, 0);
        }

        // epilogue: D col = lane&15, row = (lane>>4)*4 + q
        #pragma unroll
        for (int q = 0; q < 4; ++q) {
            int rr = m0 + g * 4 + q;
            if (rr < hi)
                out[(size_t)lst[rr] * OUTS + cc] = acc0[q] + bval;
        }
    }
}

extern "C" void kernel_launch(void* const* d_in, const int* in_sizes, int n_in,
                              void* d_out, int out_size, void* d_ws, size_t ws_size,
                              hipStream_t stream) {
    const float* x   = (const float*)d_in[0];
    // d_in[1] = var_vector (unused in forward)
    const float* W1  = (const float*)d_in[2];
    const float* b1  = (const float*)d_in[3];
    const int*   nid = (const int*)d_in[4];
    float* out = (float*)d_out;

    int* gcnt = (int*)d_ws;                                   // 128 * 4B
    unsigned short* glist = (unsigned short*)((char*)d_ws + 512);  // 128*MAXC*2B

    hipMemsetAsync(gcnt, 0, NODES * sizeof(int), stream);
    hipLaunchKernelGGL(moe_scan, dim3(BATCH / 256), dim3(256), 0, stream,
                       nid, gcnt, glist);
    hipLaunchKernelGGL(moe_fwd, dim3(NODES * (OUTS / NT) * MSPLIT), dim3(256),
                       0, stream, x, W1, b1, out, gcnt, glist);
}

// Round 5
// 25.296 us; speedup vs baseline: 1.2818x; 1.2818x over previous
//
#include <hip/hip_runtime.h>

#define BATCH 4096
#define INS   256
#define OUTS  256
#define NODES 128
#define NT    64      // output-column tile per workgroup
#define MCH   32      // sample rows per chunk (two 16-row MFMA tiles)
#define PITCH 264     // LDS row pitch in bf16 units (16B-aligned columns)

typedef short short8 __attribute__((ext_vector_type(8)));
typedef float f32x4  __attribute__((ext_vector_type(4)));

struct SMem {
    unsigned short wt[NT * PITCH];   // W^T tile: [c_local][k] bf16 (33.8 KB)
    unsigned short list[BATCH];      // sample ids for this expert (8 KB)
    int cnt;
};

__device__ __forceinline__ unsigned short f2bf(float f) {
    unsigned int u = __builtin_bit_cast(unsigned int, f);
    u += 0x7fffu + ((u >> 16) & 1u);   // round-to-nearest-even
    return (unsigned short)(u >> 16);
}

__device__ __forceinline__ short8 pack8(float4 a, float4 b) {
    short8 r;
    r[0] = (short)f2bf(a.x); r[1] = (short)f2bf(a.y);
    r[2] = (short)f2bf(a.z); r[3] = (short)f2bf(a.w);
    r[4] = (short)f2bf(b.x); r[5] = (short)f2bf(b.y);
    r[6] = (short)f2bf(b.z); r[7] = (short)f2bf(b.w);
    return r;
}

__global__ __launch_bounds__(256, 3) void moe_fwd(
    const float* __restrict__ x, const float* __restrict__ W1,
    const float* __restrict__ b1, const int* __restrict__ nid,
    float* __restrict__ out)
{
    __shared__ SMem sm;
    const int t   = threadIdx.x;
    const int bid = blockIdx.x;
    // XCD-chunked swizzle: all 4 column-quarters of an expert on one XCD
    // (L2 reuse of x rows and nid across the quarters).
    const int sub = bid >> 3;              // 0..63 within XCD
    const int e   = (bid & 7) * 16 + (sub >> 2);
    const int c0  = (sub & 3) * NT;

    const int w  = t >> 6;     // wave 0..3 -> 16-col block
    const int l  = t & 63;
    const int g  = l >> 4;     // k-group
    const int ln = l & 15;
    const int cc = c0 + w * 16 + ln;

    if (t == 0) sm.cnt = 0;
    __syncthreads();           // nothing in flight yet; cheap full barrier

    // ---- stage W tile FIRST: full-line coalesced global reads.
    // Per instruction: 64 lanes read 64 consecutive floats (256 B = 2 full
    // 128-B lines). Each thread packs 8 k's of one column -> one contiguous
    // ds_write_b128. W fetch = 33.5 MB grid-wide, exactly once. ----
    const float* __restrict__ wgp = W1 + (size_t)e * (INS * OUTS) + c0;
    #pragma unroll
    for (int it = 0; it < (NT * 32) / 256; ++it) {
        int idx = it * 256 + t;
        int c   = idx & (NT - 1);
        int kb  = idx >> 6;            // 0..31, block of 8 k's
        short8 v;
        #pragma unroll
        for (int j = 0; j < 8; ++j) {
            float f = wgp[(size_t)(kb * 8 + j) * OUTS + c];
            v[j] = (short)f2bf(f);
        }
        *reinterpret_cast<short8*>(&sm.wt[c * PITCH + kb * 8]) = v;
    }
    const float bval = b1[e * OUTS + cc];

    // ---- scan node_ind[1]; these loads queue behind the W loads in the
    // in-order vmcnt queue, so the scan's latency hides under the W drain. ----
    const int* __restrict__ idxp = nid + BATCH;
    #pragma unroll
    for (int it = 0; it < BATCH / 256; ++it) {
        int b = it * 256 + t;
        if (idxp[b] == e) {
            int p = atomicAdd(&sm.cnt, 1);
            sm.list[p] = (unsigned short)b;
        }
    }
    // LDS-only barrier: ds_writes (W tile, list) must drain; no vmcnt drain
    // needed (x loads not yet issued; W global loads already consumed).
    asm volatile("s_waitcnt lgkmcnt(0)" ::: "memory");
    __builtin_amdgcn_s_barrier();
    asm volatile("" ::: "memory");

    const int cnt = sm.cnt;
    if (cnt == 0) return;              // uniform across WG

    // ---- barrier-free chunk loop: x rows direct from global (L2-hot) ----
    for (int m0 = 0; m0 < cnt; m0 += MCH) {
        int r0 = m0 + ln;
        int r1 = m0 + 16 + ln;
        int s0 = sm.list[r0 < cnt ? r0 : cnt - 1];   // clamped tail rows only
        int s1 = sm.list[r1 < cnt ? r1 : cnt - 1];   // feed discarded D rows
        const float* __restrict__ xp0 = x + (size_t)s0 * INS + g * 8;
        const float* __restrict__ xp1 = x + (size_t)s1 * INS + g * 8;

        f32x4 acc0 = {0.f, 0.f, 0.f, 0.f};
        f32x4 acc1 = {0.f, 0.f, 0.f, 0.f};
        #pragma unroll
        for (int ks = 0; ks < 8; ++ks) {
            float4 u0 = *reinterpret_cast<const float4*>(xp0 + ks * 32);
            float4 u1 = *reinterpret_cast<const float4*>(xp0 + ks * 32 + 4);
            float4 v0 = *reinterpret_cast<const float4*>(xp1 + ks * 32);
            float4 v1 = *reinterpret_cast<const float4*>(xp1 + ks * 32 + 4);
            short8 a0 = pack8(u0, u1);
            short8 a1 = pack8(v0, v1);
            short8 bb = *reinterpret_cast<const short8*>(
                &sm.wt[(w * 16 + ln) * PITCH + ks * 32 + g * 8]);
            acc0 = __builtin_amdgcn_mfma_f32_16x16x32_bf16(a0, bb, acc0, 0, 0, 0);
            acc1 = __builtin_amdgcn_mfma_f32_16x16x32_bf16(a1, bb, acc1, 0, 0, 0);
        }

        // ---- epilogue: D col = lane&15, row = (lane>>4)*4 + q ----
        #pragma unroll
        for (int q = 0; q < 4; ++q) {
            int rr0 = m0 + g * 4 + q;
            if (rr0 < cnt)
                out[(size_t)sm.list[rr0] * OUTS + cc] = acc0[q] + bval;
            int rr1 = m0 + 16 + g * 4 + q;
            if (rr1 < cnt)
                out[(size_t)sm.list[rr1] * OUTS + cc] = acc1[q] + bval;
        }
    }
}

extern "C" void kernel_launch(void* const* d_in, const int* in_sizes, int n_in,
                              void* d_out, int out_size, void* d_ws, size_t ws_size,
                              hipStream_t stream) {
    const float* x   = (const float*)d_in[0];
    // d_in[1] = var_vector (unused in forward)
    const float* W1  = (const float*)d_in[2];
    const float* b1  = (const float*)d_in[3];
    const int*   nid = (const int*)d_in[4];
    float* out = (float*)d_out;

    hipLaunchKernelGGL(moe_fwd, dim3(NODES * (OUTS / NT)), dim3(256), 0, stream,
                       x, W1, b1, nid, out);
}

// Round 6
// 22.261 us; speedup vs baseline: 1.4565x; 1.1364x over previous
//
#include <hip/hip_runtime.h>

#define BATCH 4096
#define INS   256
#define OUTS  256
#define NODES 128
#define NT    64      // output-column tile per workgroup
#define MCH   32      // sample rows per chunk (two 16-row MFMA tiles)
#define PITCH 264     // LDS row pitch in bf16 units (16B-aligned columns)

typedef short short8 __attribute__((ext_vector_type(8)));
typedef float f32x4  __attribute__((ext_vector_type(4)));

struct SMem {
    unsigned short wt[NT * PITCH];   // W^T tile: [c_local][k] bf16 (33.8 KB)
    unsigned short list[BATCH];      // sample ids for this expert (8 KB)
    int cnt;
};

__device__ __forceinline__ unsigned short f2bf(float f) {
    unsigned int u = __builtin_bit_cast(unsigned int, f);
    u += 0x7fffu + ((u >> 16) & 1u);   // round-to-nearest-even
    return (unsigned short)(u >> 16);
}

__device__ __forceinline__ short8 pack8(float4 a, float4 b) {
    short8 r;
    r[0] = (short)f2bf(a.x); r[1] = (short)f2bf(a.y);
    r[2] = (short)f2bf(a.z); r[3] = (short)f2bf(a.w);
    r[4] = (short)f2bf(b.x); r[5] = (short)f2bf(b.y);
    r[6] = (short)f2bf(b.z); r[7] = (short)f2bf(b.w);
    return r;
}

__global__ __launch_bounds__(256, 3) void moe_fwd(
    const float* __restrict__ x, const float* __restrict__ W1,
    const float* __restrict__ b1, const int* __restrict__ nid,
    float* __restrict__ out)
{
    __shared__ SMem sm;
    const int t   = threadIdx.x;
    const int bid = blockIdx.x;
    // XCD-chunked swizzle: all 4 column-quarters of an expert on one XCD
    // (L2 reuse of x rows and nid across the quarters).
    const int sub = bid >> 3;              // 0..63 within XCD
    const int e   = (bid & 7) * 16 + (sub >> 2);
    const int c0  = (sub & 3) * NT;

    const int w  = t >> 6;     // wave 0..3 -> 16-col block
    const int l  = t & 63;
    const int g  = l >> 4;     // k-group
    const int ln = l & 15;
    const int cc = c0 + w * 16 + ln;

    if (t == 0) sm.cnt = 0;
    __syncthreads();           // nothing in flight yet; cheap full barrier

    // ---- stage W tile FIRST: full-line coalesced NON-TEMPORAL reads.
    // W is single-use: nt skips L2/L3 allocation, so no dirty poisoned
    // victim line must be written back before each miss fills. ----
    const float* __restrict__ wgp = W1 + (size_t)e * (INS * OUTS) + c0;
    #pragma unroll
    for (int it = 0; it < (NT * 32) / 256; ++it) {
        int idx = it * 256 + t;
        int c   = idx & (NT - 1);
        int kb  = idx >> 6;            // 0..31, block of 8 k's
        short8 v;
        #pragma unroll
        for (int j = 0; j < 8; ++j) {
            float f = __builtin_nontemporal_load(
                &wgp[(size_t)(kb * 8 + j) * OUTS + c]);
            v[j] = (short)f2bf(f);
        }
        *reinterpret_cast<short8*>(&sm.wt[c * PITCH + kb * 8]) = v;
    }
    const float bval = b1[e * OUTS + cc];

    // ---- scan node_ind[1]; queues behind W loads in the in-order vmcnt
    // queue so the scan tail hides under the W drain. nid is reused across
    // blocks -> keep normally cached. ----
    const int* __restrict__ idxp = nid + BATCH;
    #pragma unroll
    for (int it = 0; it < BATCH / 256; ++it) {
        int b = it * 256 + t;
        if (idxp[b] == e) {
            int p = atomicAdd(&sm.cnt, 1);
            sm.list[p] = (unsigned short)b;
        }
    }
    // LDS-only barrier: ds_writes (W tile, list) must drain; no vmcnt drain.
    asm volatile("s_waitcnt lgkmcnt(0)" ::: "memory");
    __builtin_amdgcn_s_barrier();
    asm volatile("" ::: "memory");

    const int cnt = sm.cnt;
    if (cnt == 0) return;              // uniform across WG

    // ---- barrier-free chunk loop: x rows direct from global (L2-hot,
    // reused 4x across column-quarter blocks -> normal cached loads) ----
    for (int m0 = 0; m0 < cnt; m0 += MCH) {
        int r0 = m0 + ln;
        int r1 = m0 + 16 + ln;
        int s0 = sm.list[r0 < cnt ? r0 : cnt - 1];   // clamped tail rows only
        int s1 = sm.list[r1 < cnt ? r1 : cnt - 1];   // feed discarded D rows
        const float* __restrict__ xp0 = x + (size_t)s0 * INS + g * 8;
        const float* __restrict__ xp1 = x + (size_t)s1 * INS + g * 8;

        f32x4 acc0 = {0.f, 0.f, 0.f, 0.f};
        f32x4 acc1 = {0.f, 0.f, 0.f, 0.f};
        #pragma unroll
        for (int ks = 0; ks < 8; ++ks) {
            float4 u0 = *reinterpret_cast<const float4*>(xp0 + ks * 32);
            float4 u1 = *reinterpret_cast<const float4*>(xp0 + ks * 32 + 4);
            float4 v0 = *reinterpret_cast<const float4*>(xp1 + ks * 32);
            float4 v1 = *reinterpret_cast<const float4*>(xp1 + ks * 32 + 4);
            short8 a0 = pack8(u0, u1);
            short8 a1 = pack8(v0, v1);
            short8 bb = *reinterpret_cast<const short8*>(
                &sm.wt[(w * 16 + ln) * PITCH + ks * 32 + g * 8]);
            acc0 = __builtin_amdgcn_mfma_f32_16x16x32_bf16(a0, bb, acc0, 0, 0, 0);
            acc1 = __builtin_amdgcn_mfma_f32_16x16x32_bf16(a1, bb, acc1, 0, 0, 0);
        }

        // ---- epilogue: non-temporal stores (out is single-use; skip
        // allocate + dirty-victim eviction in L2/L3) ----
        #pragma unroll
        for (int q = 0; q < 4; ++q) {
            int rr0 = m0 + g * 4 + q;
            if (rr0 < cnt)
                __builtin_nontemporal_store(acc0[q] + bval,
                    &out[(size_t)sm.list[rr0] * OUTS + cc]);
            int rr1 = m0 + 16 + g * 4 + q;
            if (rr1 < cnt)
                __builtin_nontemporal_store(acc1[q] + bval,
                    &out[(size_t)sm.list[rr1] * OUTS + cc]);
        }
    }
}

extern "C" void kernel_launch(void* const* d_in, const int* in_sizes, int n_in,
                              void* d_out, int out_size, void* d_ws, size_t ws_size,
                              hipStream_t stream) {
    const float* x   = (const float*)d_in[0];
    // d_in[1] = var_vector (unused in forward)
    const float* W1  = (const float*)d_in[2];
    const float* b1  = (const float*)d_in[3];
    const int*   nid = (const int*)d_in[4];
    float* out = (float*)d_out;

    hipLaunchKernelGGL(moe_fwd, dim3(NODES * (OUTS / NT)), dim3(256), 0, stream,
                       x, W1, b1, nid, out);
}

// Round 7
// 22.232 us; speedup vs baseline: 1.4584x; 1.0013x over previous
//
#include <hip/hip_runtime.h>

#define BATCH 4096
#define INS   256
#define OUTS  256
#define NODES 128
#define NT    64      // output-column tile per workgroup
#define MCH   32      // sample rows per chunk (two 16-row MFMA tiles)
#define PITCH 264     // LDS row pitch in bf16 units (16B-aligned, b128-aligned)

typedef short short8 __attribute__((ext_vector_type(8)));
typedef short short4v __attribute__((ext_vector_type(4)));
typedef float f32x4  __attribute__((ext_vector_type(4)));

struct SMem {
    unsigned short wt[NT * PITCH];   // W^T tile: [c_local][k] bf16 (33.8 KB)
    unsigned short list[BATCH];      // sample ids for this expert (8 KB)
    int cnt;
};

__device__ __forceinline__ unsigned short f2bf(float f) {
    unsigned int u = __builtin_bit_cast(unsigned int, f);
    u += 0x7fffu + ((u >> 16) & 1u);   // round-to-nearest-even
    return (unsigned short)(u >> 16);
}

__device__ __forceinline__ short8 pack8(float4 a, float4 b) {
    short8 r;
    r[0] = (short)f2bf(a.x); r[1] = (short)f2bf(a.y);
    r[2] = (short)f2bf(a.z); r[3] = (short)f2bf(a.w);
    r[4] = (short)f2bf(b.x); r[5] = (short)f2bf(b.y);
    r[6] = (short)f2bf(b.z); r[7] = (short)f2bf(b.w);
    return r;
}

__global__ __launch_bounds__(256, 3) void moe_fwd(
    const float* __restrict__ x, const float* __restrict__ W1,
    const float* __restrict__ b1, const int* __restrict__ nid,
    float* __restrict__ out)
{
    __shared__ SMem sm;
    const int t   = threadIdx.x;
    const int bid = blockIdx.x;
    // XCD-chunked swizzle: all 4 column-quarters of an expert on one XCD.
    const int sub = bid >> 3;              // 0..63 within XCD
    const int e   = (bid & 7) * 16 + (sub >> 2);
    const int c0  = (sub & 3) * NT;

    const int w  = t >> 6;     // wave 0..3 -> 16-col block
    const int l  = t & 63;
    const int g  = l >> 4;     // k-group
    const int ln = l & 15;
    const int cc = c0 + w * 16 + ln;

    if (t == 0) sm.cnt = 0;
    __syncthreads();           // nothing in flight yet; cheap full barrier

    // ---- stage W tile FIRST: float4 (16 B/lane) NON-TEMPORAL reads.
    // 16 vmem instructions/thread instead of 64 scalar dwords: 4x fewer
    // memory-path instructions for the same bytes. Each thread loads a
    // 4x4 f32 tile (rows kq..kq+3, cols c4..c4+3), transposes in registers,
    // writes 4 contiguous ds_write_b64 into the [c][k] LDS layout. ----
    const float* __restrict__ wgp = W1 + (size_t)e * (INS * OUTS) + c0;
    {
        const int c4 = (t & 15) * 4;        // local column quad
        const int kq = (t >> 4) * 4;        // k-quad within a 64-k pass
        #pragma unroll
        for (int pass = 0; pass < 4; ++pass) {
            const int kb = pass * 64 + kq;  // global k base of the 4x4 tile
            f32x4 v0 = __builtin_nontemporal_load(
                reinterpret_cast<const f32x4*>(&wgp[(size_t)(kb + 0) * OUTS + c4]));
            f32x4 v1 = __builtin_nontemporal_load(
                reinterpret_cast<const f32x4*>(&wgp[(size_t)(kb + 1) * OUTS + c4]));
            f32x4 v2 = __builtin_nontemporal_load(
                reinterpret_cast<const f32x4*>(&wgp[(size_t)(kb + 2) * OUTS + c4]));
            f32x4 v3 = __builtin_nontemporal_load(
                reinterpret_cast<const f32x4*>(&wgp[(size_t)(kb + 3) * OUTS + c4]));
            #pragma unroll
            for (int ci = 0; ci < 4; ++ci) {
                short4v s;
                s[0] = (short)f2bf(v0[ci]);
                s[1] = (short)f2bf(v1[ci]);
                s[2] = (short)f2bf(v2[ci]);
                s[3] = (short)f2bf(v3[ci]);
                *reinterpret_cast<short4v*>(&sm.wt[(c4 + ci) * PITCH + kb]) = s;
            }
        }
    }
    const float bval = b1[e * OUTS + cc];

    // ---- scan node_ind[1]; queues behind W loads in the in-order vmcnt
    // queue so the scan tail hides under the W drain. ----
    const int* __restrict__ idxp = nid + BATCH;
    #pragma unroll
    for (int it = 0; it < BATCH / 256; ++it) {
        int b = it * 256 + t;
        if (idxp[b] == e) {
            int p = atomicAdd(&sm.cnt, 1);
            sm.list[p] = (unsigned short)b;
        }
    }
    // LDS-only barrier: ds_writes (W tile, list) must drain; no vmcnt drain.
    asm volatile("s_waitcnt lgkmcnt(0)" ::: "memory");
    __builtin_amdgcn_s_barrier();
    asm volatile("" ::: "memory");

    const int cnt = sm.cnt;
    if (cnt == 0) return;              // uniform across WG

    // ---- barrier-free chunk loop: x rows direct from global (cached;
    // reused 4x across the column-quarter blocks on this XCD) ----
    for (int m0 = 0; m0 < cnt; m0 += MCH) {
        int r0 = m0 + ln;
        int r1 = m0 + 16 + ln;
        int s0 = sm.list[r0 < cnt ? r0 : cnt - 1];   // clamped tail rows only
        int s1 = sm.list[r1 < cnt ? r1 : cnt - 1];   // feed discarded D rows
        const float* __restrict__ xp0 = x + (size_t)s0 * INS + g * 8;
        const float* __restrict__ xp1 = x + (size_t)s1 * INS + g * 8;

        f32x4 acc0 = {0.f, 0.f, 0.f, 0.f};
        f32x4 acc1 = {0.f, 0.f, 0.f, 0.f};
        #pragma unroll
        for (int ks = 0; ks < 8; ++ks) {
            float4 u0 = *reinterpret_cast<const float4*>(xp0 + ks * 32);
            float4 u1 = *reinterpret_cast<const float4*>(xp0 + ks * 32 + 4);
            float4 v0 = *reinterpret_cast<const float4*>(xp1 + ks * 32);
            float4 v1 = *reinterpret_cast<const float4*>(xp1 + ks * 32 + 4);
            short8 a0 = pack8(u0, u1);
            short8 a1 = pack8(v0, v1);
            short8 bb = *reinterpret_cast<const short8*>(
                &sm.wt[(w * 16 + ln) * PITCH + ks * 32 + g * 8]);
            acc0 = __builtin_amdgcn_mfma_f32_16x16x32_bf16(a0, bb, acc0, 0, 0, 0);
            acc1 = __builtin_amdgcn_mfma_f32_16x16x32_bf16(a1, bb, acc1, 0, 0, 0);
        }

        // ---- epilogue: non-temporal stores (out single-use; no RFO) ----
        #pragma unroll
        for (int q = 0; q < 4; ++q) {
            int rr0 = m0 + g * 4 + q;
            if (rr0 < cnt)
                __builtin_nontemporal_store(acc0[q] + bval,
                    &out[(size_t)sm.list[rr0] * OUTS + cc]);
            int rr1 = m0 + 16 + g * 4 + q;
            if (rr1 < cnt)
                __builtin_nontemporal_store(acc1[q] + bval,
                    &out[(size_t)sm.list[rr1] * OUTS + cc]);
        }
    }
}

extern "C" void kernel_launch(void* const* d_in, const int* in_sizes, int n_in,
                              void* d_out, int out_size, void* d_ws, size_t ws_size,
                              hipStream_t stream) {
    const float* x   = (const float*)d_in[0];
    // d_in[1] = var_vector (unused in forward)
    const float* W1  = (const float*)d_in[2];
    const float* b1  = (const float*)d_in[3];
    const int*   nid = (const int*)d_in[4];
    float* out = (float*)d_out;

    hipLaunchKernelGGL(moe_fwd, dim3(NODES * (OUTS / NT)), dim3(256), 0, stream,
                       x, W1, b1, nid, out);
}

// Round 8
// 21.652 us; speedup vs baseline: 1.4975x; 1.0268x over previous
//
#include <hip/hip_runtime.h>

#define BATCH 4096
#define INS   256
#define OUTS  256
#define NODES 128
#define NT    64      // output-column tile per workgroup
#define MCH   16      // sample rows per chunk (one 16-row MFMA tile)
#define PITCH 264     // LDS row pitch in bf16 units (16B-aligned, b128-aligned)

typedef short short8 __attribute__((ext_vector_type(8)));
typedef short short4v __attribute__((ext_vector_type(4)));
typedef float f32x4  __attribute__((ext_vector_type(4)));

struct SMem {
    unsigned short wt[NT * PITCH];   // W^T tile: [c_local][k] bf16 (33.8 KB)
    unsigned short list[BATCH];      // sample ids for this expert (8 KB)
    int cnt;
};

__device__ __forceinline__ unsigned short f2bf(float f) {
    unsigned int u = __builtin_bit_cast(unsigned int, f);
    u += 0x7fffu + ((u >> 16) & 1u);   // round-to-nearest-even
    return (unsigned short)(u >> 16);
}

__device__ __forceinline__ short8 pack8(f32x4 a, f32x4 b) {
    short8 r;
    r[0] = (short)f2bf(a[0]); r[1] = (short)f2bf(a[1]);
    r[2] = (short)f2bf(a[2]); r[3] = (short)f2bf(a[3]);
    r[4] = (short)f2bf(b[0]); r[5] = (short)f2bf(b[1]);
    r[6] = (short)f2bf(b[2]); r[7] = (short)f2bf(b[3]);
    return r;
}

// Gather one chunk's x slice for this lane into registers (issue-only; the
// consuming converts later get compiler-counted vmcnt waits). Tail rows are
// zero-filled: their D rows are discarded by the predicated store.
__device__ __forceinline__ void pf_x(const float* __restrict__ x,
                                     const unsigned short* lst, int m0, int hi,
                                     int ln, int g, f32x4 xr[8][2]) {
    int r = m0 + ln;
    if (r < hi) {
        const float* __restrict__ xp = x + (size_t)lst[r] * INS + g * 8;
        #pragma unroll
        for (int ks = 0; ks < 8; ++ks) {
            xr[ks][0] = *reinterpret_cast<const f32x4*>(xp + ks * 32);
            xr[ks][1] = *reinterpret_cast<const f32x4*>(xp + ks * 32 + 4);
        }
    } else {
        #pragma unroll
        for (int ks = 0; ks < 8; ++ks) {
            xr[ks][0] = (f32x4){0.f, 0.f, 0.f, 0.f};
            xr[ks][1] = (f32x4){0.f, 0.f, 0.f, 0.f};
        }
    }
}

__global__ __launch_bounds__(256, 2) void moe_fwd(
    const float* __restrict__ x, const float* __restrict__ W1,
    const float* __restrict__ b1, const int* __restrict__ nid,
    float* __restrict__ out)
{
    __shared__ SMem sm;
    const int t   = threadIdx.x;
    const int bid = blockIdx.x;
    // XCD-chunked swizzle: all 4 column-quarters of an expert on one XCD.
    const int sub = bid >> 3;              // 0..63 within XCD
    const int e   = (bid & 7) * 16 + (sub >> 2);
    const int c0  = (sub & 3) * NT;

    const int w  = t >> 6;     // wave 0..3 -> 16-col block
    const int l  = t & 63;
    const int g  = l >> 4;     // k-group
    const int ln = l & 15;
    const int cc = c0 + w * 16 + ln;

    if (t == 0) sm.cnt = 0;
    __syncthreads();

    // ---- 1) scan FIRST: nid is 16 KB (L2-amortized across 64 blocks/XCD).
    // Resolves the list dependency before any HBM-heavy traffic is queued,
    // so the x gather can be ISSUED early instead of after the W drain. ----
    const int* __restrict__ idxp = nid + BATCH;
    #pragma unroll
    for (int it = 0; it < BATCH / 256; ++it) {
        int b = it * 256 + t;
        if (idxp[b] == e) {
            int p = atomicAdd(&sm.cnt, 1);
            sm.list[p] = (unsigned short)b;
        }
    }
    asm volatile("s_waitcnt lgkmcnt(0)" ::: "memory");
    __builtin_amdgcn_s_barrier();
    asm volatile("" ::: "memory");

    const int cnt = sm.cnt;
    if (cnt == 0) return;              // uniform across WG

    // ---- 2) issue W nt loads (float4, full-line, 16 instrs/thread), raw
    // f32 held in registers; do NOT consume yet. ----
    const float* __restrict__ wgp = W1 + (size_t)e * (INS * OUTS) + c0;
    const int c4 = (t & 15) * 4;
    const int kq = (t >> 4) * 4;
    f32x4 wr[16];
    #pragma unroll
    for (int pass = 0; pass < 4; ++pass) {
        const int kb = pass * 64 + kq;
        #pragma unroll
        for (int j = 0; j < 4; ++j)
            wr[pass * 4 + j] = __builtin_nontemporal_load(
                reinterpret_cast<const f32x4*>(&wgp[(size_t)(kb + j) * OUTS + c4]));
    }
    const float bval = b1[e * OUTS + cc];

    // ---- 3) issue chunk-0 x gather NOW: joins the HBM queue right behind W
    // instead of serially after the whole W drain + convert + barrier. ----
    f32x4 xA[8][2], xB[8][2];
    pf_x(x, sm.list, 0, cnt, ln, g, xA);

    // ---- 4) consume W (counted vmcnt waits: W loads are oldest; the x
    // loads above stay in flight), transpose 4x4 in regs, stage to LDS. ----
    #pragma unroll
    for (int pass = 0; pass < 4; ++pass) {
        const int kb = pass * 64 + kq;
        #pragma unroll
        for (int ci = 0; ci < 4; ++ci) {
            short4v s;
            s[0] = (short)f2bf(wr[pass * 4 + 0][ci]);
            s[1] = (short)f2bf(wr[pass * 4 + 1][ci]);
            s[2] = (short)f2bf(wr[pass * 4 + 2][ci]);
            s[3] = (short)f2bf(wr[pass * 4 + 3][ci]);
            *reinterpret_cast<short4v*>(&sm.wt[(c4 + ci) * PITCH + kb]) = s;
        }
    }
    asm volatile("s_waitcnt lgkmcnt(0)" ::: "memory");
    __builtin_amdgcn_s_barrier();
    asm volatile("" ::: "memory");

    // ---- 5) chunk loop, register-double-buffered x (no LDS, no barriers):
    // chunk c+1's gather is in flight during chunk c's MFMA + stores. ----
    for (int m0 = 0; m0 < cnt; m0 += MCH) {
        const bool more = (m0 + MCH) < cnt;
        if (more) pf_x(x, sm.list, m0 + MCH, cnt, ln, g, xB);

        f32x4 acc = {0.f, 0.f, 0.f, 0.f};
        #pragma unroll
        for (int ks = 0; ks < 8; ++ks) {
            short8 a0 = pack8(xA[ks][0], xA[ks][1]);
            short8 bb = *reinterpret_cast<const short8*>(
                &sm.wt[(w * 16 + ln) * PITCH + ks * 32 + g * 8]);
            acc = __builtin_amdgcn_mfma_f32_16x16x32_bf16(a0, bb, acc, 0, 0, 0);
        }

        // epilogue: D col = lane&15, row = (lane>>4)*4 + q; nt stores.
        #pragma unroll
        for (int q = 0; q < 4; ++q) {
            int rr = m0 + g * 4 + q;
            if (rr < cnt)
                __builtin_nontemporal_store(acc[q] + bval,
                    &out[(size_t)sm.list[rr] * OUTS + cc]);
        }

        if (more) {
            #pragma unroll
            for (int ks = 0; ks < 8; ++ks) {
                xA[ks][0] = xB[ks][0];
                xA[ks][1] = xB[ks][1];
            }
        }
    }
}

extern "C" void kernel_launch(void* const* d_in, const int* in_sizes, int n_in,
                              void* d_out, int out_size, void* d_ws, size_t ws_size,
                              hipStream_t stream) {
    const float* x   = (const float*)d_in[0];
    // d_in[1] = var_vector (unused in forward)
    const float* W1  = (const float*)d_in[2];
    const float* b1  = (const float*)d_in[3];
    const int*   nid = (const int*)d_in[4];
    float* out = (float*)d_out;

    hipLaunchKernelGGL(moe_fwd, dim3(NODES * (OUTS / NT)), dim3(256), 0, stream,
                       x, W1, b1, nid, out);
}